// Round 10
// baseline (309.166 us; speedup 1.0000x reference)
//
#include <hip/hip_runtime.h>

static constexpr int N  = 98304;
static constexpr int D  = 128;
static constexpr int E  = 491520;
static constexpr int B  = 16384;

using f32x4 = __attribute__((ext_vector_type(4))) float;
using s16x8 = __attribute__((ext_vector_type(8))) short;

typedef __attribute__((address_space(3))) void lds_void;
typedef const __attribute__((address_space(1))) void gbl_void;

__device__ __forceinline__ ushort f2bf(float x) {
    unsigned u = __float_as_uint(x);
    return (ushort)((u + 0x7fffu + ((u >> 16) & 1u)) >> 16);
}
__device__ __forceinline__ float bflo(unsigned u) { return __uint_as_float(u << 16); }
__device__ __forceinline__ float bfhi(unsigned u) { return __uint_as_float(u & 0xffff0000u); }

// ---- setup: zero both histogram arrays (cnt[N] | vcnt[B] contiguous) ----
__global__ void zero2_kernel(int* __restrict__ p) {
    int i = blockIdx.x * 256 + threadIdx.x;
    if (i < N + B) p[i] = 0;
}

// ---- dual histogram: edges by dest, nodes by view ----
__global__ void hist2_kernel(const int* __restrict__ eto, const int* __restrict__ view,
                             int* __restrict__ cnt, int* __restrict__ vcnt) {
    int gid = blockIdx.x * 256 + threadIdx.x;
    if (gid < E) atomicAdd(&cnt[eto[gid]], 1);
    else if (gid < E + N) atomicAdd(&vcnt[view[gid - E]], 1);
}

// ---- dual scan, stage 1: blocks 0..95 nodes (PADDED to mult-of-4), 96..111 views ----
__global__ __launch_bounds__(256) void scan1_kernel(const int* __restrict__ cnt, int* __restrict__ excl,
                                                    const int* __restrict__ vcnt, int* __restrict__ vexcl,
                                                    int* __restrict__ bsum) {
    __shared__ int s[256];
    const int b = blockIdx.x, t = threadIdx.x;
    const int* src; int* dst; int base;
    bool pad = (b < 96);
    if (pad) { src = cnt;  dst = excl;  base = b * 1024 + t * 4; }
    else     { src = vcnt; dst = vexcl; base = (b - 96) * 1024 + t * 4; }
    int4 v = *reinterpret_cast<const int4*>(src + base);
    if (pad) { v.x = (v.x + 3) & ~3; v.y = (v.y + 3) & ~3; v.z = (v.z + 3) & ~3; v.w = (v.w + 3) & ~3; }
    int local = v.x + v.y + v.z + v.w;
    s[t] = local; __syncthreads();
    for (int off = 1; off < 256; off <<= 1) {
        int x = (t >= off) ? s[t - off] : 0;
        __syncthreads();
        s[t] += x;
        __syncthreads();
    }
    int excl_t = s[t] - local;
    if (t == 255) bsum[b] = s[t];
    int4 o;
    o.x = excl_t; o.y = o.x + v.x; o.z = o.y + v.y; o.w = o.z + v.z;
    *reinterpret_cast<int4*>(dst + base) = o;
}

// Parallel dual-segment scan of bsum[0..95] and bsum[96..111].
__global__ __launch_bounds__(128) void scan2_kernel(int* __restrict__ bsum) {
    __shared__ int s[128];
    const int t = threadIdx.x;
    int val = (t < 112) ? bsum[t] : 0;
    s[t] = val;
    __syncthreads();
    #pragma unroll
    for (int off = 1; off < 128; off <<= 1) {
        int x = (t >= off) ? s[t - off] : 0;
        __syncthreads();
        s[t] += x;
        __syncthreads();
    }
    int incl = s[t];
    int seg0_total = s[95];
    int excl = incl - val;
    if (t < 96) bsum[t] = excl;
    else if (t < 112) bsum[t] = excl - seg0_total;
}

__global__ void scan3_kernel(int* __restrict__ excl, int* __restrict__ vexcl,
                             const int* __restrict__ bsum) {
    int b = blockIdx.x, t = threadIdx.x;
    if (b < 384) { int i = b * 256 + t; excl[i] += bsum[i >> 10]; }
    else         { int i = (b - 384) * 256 + t; vexcl[i] += bsum[96 + (i >> 10)]; }
}

__global__ void scatter2_kernel(const int* __restrict__ efrom, const int* __restrict__ eto,
                                const int* __restrict__ view,
                                int* __restrict__ ecur, int* __restrict__ vcur,
                                int* __restrict__ sfrom, int* __restrict__ perm) {
    int gid = blockIdx.x * 256 + threadIdx.x;
    if (gid < E) {
        int p = atomicAdd(&ecur[eto[gid]], 1);
        sfrom[p] = efrom[gid];
    } else if (gid < E + N) {
        int n = gid - E;
        int p = atomicAdd(&vcur[view[n]], 1);
        perm[p] = n;
    }
}

// Fill pad slots [cur[v], roundup4(cur[v])) with sentinel index N.
__global__ void fillpad_kernel(const int* __restrict__ cur, int* __restrict__ sfrom) {
    int v = blockIdx.x * 256 + threadIdx.x;
    if (v >= N) return;
    int c = cur[v], e = (c + 3) & ~3;
    for (; c < e; ++c) sfrom[c] = N;
}

// Z row N = bf16 -inf: relu(-inf + V) = 0, so pad edges contribute nothing.
__global__ void sentinel_kernel(ushort* __restrict__ Z) {
    Z[(size_t)N * 256 + threadIdx.x] = 0xFF80;
}

// ---- weight conversion ----
__global__ void convUV_kernel(const float* __restrict__ Wm, ushort* __restrict__ Wf) {
    int gid = blockIdx.x * 256 + threadIdx.x;
    if (gid >= 3 * 32768) return;
    int r = gid >> 15, rem = gid & 32767;
    int j = rem & 7, lane = (rem >> 3) & 63, grp = rem >> 9;
    int kt = grp >> 4, nt = grp & 15;
    int n = (nt & 7) * 16 + (lane & 15);
    int k = kt * 32 + (lane >> 4) * 8 + j;
    int col = ((nt >> 3) << 7) + k;
    Wf[gid] = f2bf(Wm[((size_t)r * 128 + n) * 256 + col]);
}

__global__ void convW12_kernel(const float* __restrict__ W1, const float* __restrict__ W2,
                               ushort* __restrict__ Wb12) {
    int gid = blockIdx.x * 256 + threadIdx.x;
    if (gid >= 2 * 16384) return;
    int w = gid >> 14, rem = gid & 16383;
    int n = rem >> 7, k = rem & 127;
    int kt = k >> 5, nt = n >> 4;
    int lane = (n & 15) + (((k >> 3) & 3) << 4);
    int j = k & 7;
    const float* W = w ? W2 : W1;
    Wb12[w * 16384 + ((kt * 8 + nt) * 64 + lane) * 8 + j] = f2bf(W[rem]);
}

// ---- per-round dense GEMM: Z[v][0:128]=A[v]@Wf^T (U), Z[v][128:256]=A[v]@Wt^T+bm (V) ----
__global__ __launch_bounds__(512) void uv_kernel(
    const float* __restrict__ Asrc, ushort* __restrict__ Z,
    const ushort* __restrict__ Wft, const float* __restrict__ bm_r)
{
    __shared__ alignas(16) ushort wlds[32768];   // 64 KB
    const int t = threadIdx.x;

    #pragma unroll
    for (int it = 0; it < 8; ++it) {
        int idx = t + it * 512;
        __builtin_amdgcn_global_load_lds((gbl_void*)(Wft + idx * 8),
                                         (lds_void*)(wlds + idx * 8), 16, 0, 0);
    }

    const int wave = t >> 6, lane = t & 63;
    const int col16 = lane & 15, kq = lane >> 4;
    const int arow = blockIdx.x * 128 + wave * 16 + col16;

    const float4* Ar = reinterpret_cast<const float4*>(Asrc + (size_t)arow * 128);
    float4 areg[8];
    #pragma unroll
    for (int kt = 0; kt < 4; ++kt) {
        areg[2 * kt]     = Ar[kt * 8 + kq * 2];
        areg[2 * kt + 1] = Ar[kt * 8 + kq * 2 + 1];
    }

    f32x4 acc[16];
    #pragma unroll
    for (int nt = 0; nt < 16; ++nt) acc[nt] = (f32x4){0.f, 0.f, 0.f, 0.f};

    __syncthreads();   // wlds ready

    const char* wb = reinterpret_cast<const char*>(wlds);
    #pragma unroll
    for (int kt = 0; kt < 4; ++kt) {
        float4 a0 = areg[2 * kt], a1 = areg[2 * kt + 1];
        union { s16x8 v; ushort u[8]; } pk;
        pk.u[0] = f2bf(a0.x); pk.u[1] = f2bf(a0.y); pk.u[2] = f2bf(a0.z); pk.u[3] = f2bf(a0.w);
        pk.u[4] = f2bf(a1.x); pk.u[5] = f2bf(a1.y); pk.u[6] = f2bf(a1.z); pk.u[7] = f2bf(a1.w);
        #pragma unroll
        for (int nt = 0; nt < 16; ++nt) {
            s16x8 wfr = *reinterpret_cast<const s16x8*>(wb + (((kt * 16 + nt) * 64 + lane) << 4));
            acc[nt] = __builtin_amdgcn_mfma_f32_16x16x32_bf16(wfr, pk.v, acc[nt], 0, 0, 0);
        }
    }

    ushort* zr = Z + (size_t)arow * 256;
    #pragma unroll
    for (int nt = 0; nt < 16; ++nt) {
        float4 bq;
        if (nt >= 8) bq = *reinterpret_cast<const float4*>(bm_r + (nt - 8) * 16 + kq * 4);
        else         bq = (float4){0.f, 0.f, 0.f, 0.f};
        union { uint2 d; ushort u[4]; } pk4;
        pk4.u[0] = f2bf(acc[nt][0] + bq.x);
        pk4.u[1] = f2bf(acc[nt][1] + bq.y);
        pk4.u[2] = f2bf(acc[nt][2] + bq.z);
        pk4.u[3] = f2bf(acc[nt][3] + bq.w);
        int cbase = ((nt >> 3) << 7) + (nt & 7) * 16 + kq * 4;
        *reinterpret_cast<uint2*>(zr + cbase) = pk4.d;
    }
}

// ---- edge pass: 16 nodes/block, 4 nodes/wave; padded runs (mult-of-4, sentinel) ----
// No masks, no tails. First chunk of all 4 nodes prefetched -> 16 loads in flight.
// L[v] = Lsrc[v] + scale * sum_{e->v} relu(U[from_e] + V[v])
__global__ __launch_bounds__(256) void edge_sum_kernel(
    const ushort* __restrict__ Z, const float* __restrict__ Lsrc, float* __restrict__ Ldst,
    const int* __restrict__ sfrom, const int* __restrict__ ends, const int* __restrict__ ch_ptr)
{
    const int t = threadIdx.x;
    const int wave = t >> 6, lane = t & 63;
    const float scale = 1.0f / (float)(ch_ptr[0] - 1);
    const int v0 = blockIdx.x * 16 + wave * 4;

    // padded bounds: roundup4 of post-scatter cursors
    int bnd[5];
    bnd[0] = (v0 == 0) ? 0 : ((ends[v0 - 1] + 3) & ~3);
    #pragma unroll
    for (int i = 0; i < 4; ++i) bnd[i + 1] = (ends[v0 + i] + 3) & ~3;

    unsigned vv[4]; float2 lold[4];
    #pragma unroll
    for (int i = 0; i < 4; ++i) {
        vv[i] = *reinterpret_cast<const unsigned*>(Z + (size_t)(v0 + i) * 256 + 128 + lane * 2);
        lold[i] = *reinterpret_cast<const float2*>(Lsrc + (size_t)(v0 + i) * 128 + lane * 2);
    }

    // first-chunk prefetch: 16 indices (wave-uniform addrs), then 16 U loads in flight
    int idx[4][4];
    #pragma unroll
    for (int i = 0; i < 4; ++i) {
        #pragma unroll
        for (int k = 0; k < 4; ++k) {
            int c = bnd[i] + k;
            idx[i][k] = (c < bnd[i + 1]) ? sfrom[c] : N;   // select only fires for deg==0
        }
    }
    unsigned u[4][4];
    #pragma unroll
    for (int i = 0; i < 4; ++i)
        #pragma unroll
        for (int k = 0; k < 4; ++k)
            u[i][k] = *reinterpret_cast<const unsigned*>(Z + (size_t)idx[i][k] * 256 + lane * 2);

    #pragma unroll
    for (int i = 0; i < 4; ++i) {
        const float vl = bflo(vv[i]), vh = bfhi(vv[i]);
        float a0 = 0.f, a1 = 0.f;
        #pragma unroll
        for (int k = 0; k < 4; ++k) {
            a0 += fmaxf(bflo(u[i][k]) + vl, 0.f);
            a1 += fmaxf(bfhi(u[i][k]) + vh, 0.f);
        }
        // remaining chunks: unmasked 4-wide (pads hit the -inf sentinel row)
        for (int e = bnd[i] + 4; e < bnd[i + 1]; e += 4) {
            int f0 = sfrom[e], f1 = sfrom[e + 1], f2 = sfrom[e + 2], f3 = sfrom[e + 3];
            unsigned w0 = *reinterpret_cast<const unsigned*>(Z + (size_t)f0 * 256 + lane * 2);
            unsigned w1 = *reinterpret_cast<const unsigned*>(Z + (size_t)f1 * 256 + lane * 2);
            unsigned w2 = *reinterpret_cast<const unsigned*>(Z + (size_t)f2 * 256 + lane * 2);
            unsigned w3 = *reinterpret_cast<const unsigned*>(Z + (size_t)f3 * 256 + lane * 2);
            a0 += fmaxf(bflo(w0) + vl, 0.f) + fmaxf(bflo(w1) + vl, 0.f)
                + fmaxf(bflo(w2) + vl, 0.f) + fmaxf(bflo(w3) + vl, 0.f);
            a1 += fmaxf(bfhi(w0) + vh, 0.f) + fmaxf(bfhi(w1) + vh, 0.f)
                + fmaxf(bfhi(w2) + vh, 0.f) + fmaxf(bfhi(w3) + vh, 0.f);
        }
        float2 o;
        o.x = lold[i].x + scale * a0;
        o.y = lold[i].y + scale * a1;
        *reinterpret_cast<float2*>(Ldst + (size_t)(v0 + i) * 128 + lane * 2) = o;
    }
}

// ---- segment sum via view-sorted perm: one wave per view, no atomics ----
__global__ __launch_bounds__(256) void segsum_sorted_kernel(
    const float* __restrict__ L, const int* __restrict__ perm,
    const int* __restrict__ vends, float* __restrict__ y)
{
    const int t = threadIdx.x;
    const int wave = t >> 6, lane = t & 63;
    const int v = blockIdx.x * 4 + wave;
    const int lo = (v == 0) ? 0 : vends[v - 1];
    const int hi = vends[v];

    float a0 = 0.f, a1 = 0.f;
    for (int e = lo; e < hi; e += 2) {
        int last = hi - 1;
        int e1 = (e + 1 < hi) ? e + 1 : last;
        float m1 = (e + 1 < hi) ? 1.f : 0.f;
        int n0 = perm[e], n1 = perm[e1];
        float2 x0 = *reinterpret_cast<const float2*>(L + (size_t)n0 * 128 + lane * 2);
        float2 x1 = *reinterpret_cast<const float2*>(L + (size_t)n1 * 128 + lane * 2);
        a0 += x0.x + m1 * x1.x;
        a1 += x0.y + m1 * x1.y;
    }
    float2 o; o.x = a0; o.y = a1;
    *reinterpret_cast<float2*>(y + (size_t)v * 128 + lane * 2) = o;
}

// ---- fused readout: reads y (ws), writes final output to d_out ----
__global__ __launch_bounds__(256) void readout_mfma_kernel(
    const float* __restrict__ y, float* __restrict__ outp,
    const ushort* __restrict__ Wb1, const ushort* __restrict__ Wb2,
    const float* __restrict__ b1, const float* __restrict__ b2)
{
    __shared__ alignas(16) ushort hs[64 * 128];
    const int t = threadIdx.x;
    const int r0 = blockIdx.x * 64;
    char* hbase = reinterpret_cast<char*>(hs);
    const float4* y4 = reinterpret_cast<const float4*>(y);

    #pragma unroll
    for (int it = 0; it < 4; ++it) {
        int c = t + it * 256;
        int e = c >> 4, p = c & 15;
        int g = p ^ (e & 15);
        float4 a = y4[(size_t)(r0 + e) * 32 + g * 2];
        float4 bq = y4[(size_t)(r0 + e) * 32 + g * 2 + 1];
        union { s16x8 v; ushort u[8]; } pk;
        pk.u[0] = f2bf(a.x); pk.u[1] = f2bf(a.y); pk.u[2] = f2bf(a.z); pk.u[3] = f2bf(a.w);
        pk.u[4] = f2bf(bq.x); pk.u[5] = f2bf(bq.y); pk.u[6] = f2bf(bq.z); pk.u[7] = f2bf(bq.w);
        *reinterpret_cast<s16x8*>(hbase + e * 256 + p * 16) = pk.v;
    }
    __syncthreads();

    const int wave = t >> 6, lane = t & 63;
    const int rrow = wave * 16 + (lane & 15);
    const int kq = lane >> 4;
    const int rx = rrow & 15;
    const char* hrow = hbase + rrow * 256;
    const int col16 = lane & 15;

    f32x4 acc[8];
    #pragma unroll
    for (int nt = 0; nt < 8; ++nt) acc[nt] = (f32x4){0.f, 0.f, 0.f, 0.f};
    const s16x8* wf1 = reinterpret_cast<const s16x8*>(Wb1);
    #pragma unroll
    for (int kt = 0; kt < 4; ++kt) {
        int C = kt * 4 + kq;
        s16x8 a = *reinterpret_cast<const s16x8*>(hrow + ((C ^ rx) & 15) * 16);
        #pragma unroll
        for (int nt = 0; nt < 8; ++nt)
            acc[nt] = __builtin_amdgcn_mfma_f32_16x16x32_bf16(a, wf1[(kt * 8 + nt) * 64 + lane], acc[nt], 0, 0, 0);
    }
    __syncthreads();

    #pragma unroll
    for (int nt = 0; nt < 8; ++nt) {
        float bias = b1[nt * 16 + col16];
        #pragma unroll
        for (int j = 0; j < 4; ++j) {
            int r = wave * 16 + (lane >> 4) * 4 + j;
            float h = fmaxf(acc[nt][j] + bias, 0.f);
            int colfull = nt * 16 + col16;
            int chunk = colfull >> 3;
            int bo = ((chunk ^ (r & 15)) * 16) + (colfull & 7) * 2;
            *reinterpret_cast<ushort*>(hbase + r * 256 + bo) = f2bf(h);
        }
    }
    __syncthreads();

    f32x4 acc2[8];
    #pragma unroll
    for (int nt = 0; nt < 8; ++nt) acc2[nt] = (f32x4){0.f, 0.f, 0.f, 0.f};
    const s16x8* wf2 = reinterpret_cast<const s16x8*>(Wb2);
    #pragma unroll
    for (int kt = 0; kt < 4; ++kt) {
        int C = kt * 4 + kq;
        s16x8 a = *reinterpret_cast<const s16x8*>(hrow + ((C ^ rx) & 15) * 16);
        #pragma unroll
        for (int nt = 0; nt < 8; ++nt)
            acc2[nt] = __builtin_amdgcn_mfma_f32_16x16x32_bf16(a, wf2[(kt * 8 + nt) * 64 + lane], acc2[nt], 0, 0, 0);
    }

    #pragma unroll
    for (int nt = 0; nt < 8; ++nt) {
        float bias = b2[nt * 16 + col16];
        #pragma unroll
        for (int j = 0; j < 4; ++j) {
            int r = r0 + wave * 16 + (lane >> 4) * 4 + j;
            outp[(size_t)r * 128 + nt * 16 + col16] = acc2[nt][j] + bias;
        }
    }
}

extern "C" void kernel_launch(void* const* d_in, const int* in_sizes, int n_in,
                              void* d_out, int out_size, void* d_ws, size_t ws_size,
                              hipStream_t stream) {
    const float* latents = (const float*)d_in[0];
    const float* Wm      = (const float*)d_in[1];
    const float* bm      = (const float*)d_in[2];
    const float* W1      = (const float*)d_in[3];
    const float* b1      = (const float*)d_in[4];
    const float* W2      = (const float*)d_in[5];
    const float* b2      = (const float*)d_in[6];
    const int*   efrom   = (const int*)d_in[7];
    const int*   eto     = (const int*)d_in[8];
    const int*   view    = (const int*)d_in[9];
    const int*   ch      = (const int*)d_in[10];

    // ws: L f32[N*128] | Z bf16[(N+1)*256] (row N = -inf sentinel).
    // After final edge_sum Z rows [0,N) are dead: y f32[B*128] and Wb12 reuse them.
    float*  L  = (float*)d_ws;
    ushort* Z  = (ushort*)(L + (size_t)N * D);
    float*  yb = (float*)Z;                              // B*128 f32 = 8.39 MB
    ushort* Wb12 = (ushort*)((char*)Z + 8388608);        // 64 KB

    // d_out scratch (readout is d_out's only writer, covers all of it):
    char* ob = (char*)d_out;
    ushort* WUVf = (ushort*)ob;                          // 196,608 B
    int* cnt   = (int*)(ob + 196608);                    // N
    int* vcnt  = cnt + N;                                // B
    int* excl  = vcnt + B;                               // N
    int* vexcl = excl + N;                               // B
    int* bsum  = vexcl + B;                              // 112 (+pad)
    int* sfrom = bsum + 128;                             // E + 3N (padded)
    int* perm  = sfrom + E + 3 * N;                      // N    (total ~4.7 MB < 8.39 MB)
    float* outp = (float*)d_out;

    // Setup: weight frags + dual counting sort (edges by dest PADDED, nodes by view).
    convUV_kernel<<<384, 256, 0, stream>>>(Wm, WUVf);
    zero2_kernel<<<(N + B) / 256, 256, 0, stream>>>(cnt);
    hist2_kernel<<<(E + N) / 256, 256, 0, stream>>>(eto, view, cnt, vcnt);
    scan1_kernel<<<112, 256, 0, stream>>>(cnt, excl, vcnt, vexcl, bsum);
    scan2_kernel<<<1, 128, 0, stream>>>(bsum);
    scan3_kernel<<<448, 256, 0, stream>>>(excl, vexcl, bsum);
    scatter2_kernel<<<(E + N) / 256, 256, 0, stream>>>(efrom, eto, view, excl, vexcl, sfrom, perm);
    fillpad_kernel<<<N / 256, 256, 0, stream>>>(excl, sfrom);
    sentinel_kernel<<<1, 256, 0, stream>>>(Z);
    // post-scatter: excl[v] = pstart[v]+deg[v]; padded bounds = roundup4 in-kernel

    // Three message-passing rounds.
    uv_kernel<<<N / 128, 512, 0, stream>>>(latents, Z, WUVf, bm);
    edge_sum_kernel<<<N / 16, 256, 0, stream>>>(Z, latents, L, sfrom, excl, ch);
    uv_kernel<<<N / 128, 512, 0, stream>>>(L, Z, WUVf + 32768, bm + D);
    edge_sum_kernel<<<N / 16, 256, 0, stream>>>(Z, L, L, sfrom, excl, ch);
    uv_kernel<<<N / 128, 512, 0, stream>>>(L, Z, WUVf + 65536, bm + 2 * D);
    edge_sum_kernel<<<N / 16, 256, 0, stream>>>(Z, L, L, sfrom, excl, ch);

    // Readout: Z dead -> yb/Wb12 live there.
    convW12_kernel<<<128, 256, 0, stream>>>(W1, W2, Wb12);
    segsum_sorted_kernel<<<B / 4, 256, 0, stream>>>(L, perm, vexcl, yb);
    readout_mfma_kernel<<<B / 64, 256, 0, stream>>>(yb, outp, Wb12, Wb12 + 16384, b1, b2);
}

// Round 11
// 286.774 us; speedup vs baseline: 1.0781x; 1.0781x over previous
//
#include <hip/hip_runtime.h>

static constexpr int N  = 98304;
static constexpr int D  = 128;
static constexpr int E  = 491520;
static constexpr int B  = 16384;
static constexpr int SFN = E + 4 * N + 64;   // padded sfrom capacity

using f32x4 = __attribute__((ext_vector_type(4))) float;
using s16x8 = __attribute__((ext_vector_type(8))) short;

typedef __attribute__((address_space(3))) void lds_void;
typedef const __attribute__((address_space(1))) void gbl_void;

__device__ __forceinline__ ushort f2bf(float x) {
    unsigned u = __float_as_uint(x);
    return (ushort)((u + 0x7fffu + ((u >> 16) & 1u)) >> 16);
}
__device__ __forceinline__ float bflo(unsigned u) { return __uint_as_float(u << 16); }
__device__ __forceinline__ float bfhi(unsigned u) { return __uint_as_float(u & 0xffff0000u); }

// ---- setup: zero histograms AND pre-fill sfrom with sentinel N ----
__global__ void setup_fill_kernel(int* __restrict__ cnt, int* __restrict__ sfrom) {
    int i = blockIdx.x * blockDim.x + threadIdx.x;
    int stride = gridDim.x * blockDim.x;
    for (int j = i; j < N + B; j += stride) cnt[j] = 0;
    for (int j = i; j < SFN; j += stride) sfrom[j] = N;
}

// ---- dual histogram: edges by dest, nodes by view ----
__global__ void hist2_kernel(const int* __restrict__ eto, const int* __restrict__ view,
                             int* __restrict__ cnt, int* __restrict__ vcnt) {
    int gid = blockIdx.x * 256 + threadIdx.x;
    if (gid < E) atomicAdd(&cnt[eto[gid]], 1);
    else if (gid < E + N) atomicAdd(&vcnt[view[gid - E]], 1);
}

// ---- dual scan, stage 1: blocks 0..95 nodes (pad to max(4, roundup4)), 96..111 views ----
__global__ __launch_bounds__(256) void scan1_kernel(const int* __restrict__ cnt, int* __restrict__ excl,
                                                    const int* __restrict__ vcnt, int* __restrict__ vexcl,
                                                    int* __restrict__ bsum) {
    __shared__ int s[256];
    const int b = blockIdx.x, t = threadIdx.x;
    const int* src; int* dst; int base;
    bool pad = (b < 96);
    if (pad) { src = cnt;  dst = excl;  base = b * 1024 + t * 4; }
    else     { src = vcnt; dst = vexcl; base = (b - 96) * 1024 + t * 4; }
    int4 v = *reinterpret_cast<const int4*>(src + base);
    if (pad) {
        v.x = (v.x == 0) ? 4 : ((v.x + 3) & ~3);
        v.y = (v.y == 0) ? 4 : ((v.y + 3) & ~3);
        v.z = (v.z == 0) ? 4 : ((v.z + 3) & ~3);
        v.w = (v.w == 0) ? 4 : ((v.w + 3) & ~3);
    }
    int local = v.x + v.y + v.z + v.w;
    s[t] = local; __syncthreads();
    for (int off = 1; off < 256; off <<= 1) {
        int x = (t >= off) ? s[t - off] : 0;
        __syncthreads();
        s[t] += x;
        __syncthreads();
    }
    int excl_t = s[t] - local;
    if (t == 255) bsum[b] = s[t];
    int4 o;
    o.x = excl_t; o.y = o.x + v.x; o.z = o.y + v.y; o.w = o.z + v.z;
    *reinterpret_cast<int4*>(dst + base) = o;
}

// Parallel dual-segment scan of bsum[0..95] and bsum[96..111].
__global__ __launch_bounds__(128) void scan2_kernel(int* __restrict__ bsum) {
    __shared__ int s[128];
    const int t = threadIdx.x;
    int val = (t < 112) ? bsum[t] : 0;
    s[t] = val;
    __syncthreads();
    #pragma unroll
    for (int off = 1; off < 128; off <<= 1) {
        int x = (t >= off) ? s[t - off] : 0;
        __syncthreads();
        s[t] += x;
        __syncthreads();
    }
    int incl = s[t];
    int seg0_total = s[95];
    int excl = incl - val;
    if (t < 96) bsum[t] = excl;
    else if (t < 112) bsum[t] = excl - seg0_total;
}

__global__ void scan3_kernel(int* __restrict__ excl, int* __restrict__ vexcl,
                             const int* __restrict__ bsum) {
    int b = blockIdx.x, t = threadIdx.x;
    if (b < 384) { int i = b * 256 + t; excl[i] += bsum[i >> 10]; }
    else         { int i = (b - 384) * 256 + t; vexcl[i] += bsum[96 + (i >> 10)]; }
}

__global__ void scatter2_kernel(const int* __restrict__ efrom, const int* __restrict__ eto,
                                const int* __restrict__ view,
                                int* __restrict__ ecur, int* __restrict__ vcur,
                                int* __restrict__ sfrom, int* __restrict__ perm) {
    int gid = blockIdx.x * 256 + threadIdx.x;
    if (gid < E) {
        int p = atomicAdd(&ecur[eto[gid]], 1);
        sfrom[p] = efrom[gid];
    } else if (gid < E + N) {
        int n = gid - E;
        int p = atomicAdd(&vcur[view[n]], 1);
        perm[p] = n;
    }
}

// ---- weight conversion (+ Z sentinel row write, folded in) ----
__global__ void convUV_kernel(const float* __restrict__ Wm, ushort* __restrict__ Wf,
                              ushort* __restrict__ Z) {
    int gid = blockIdx.x * 256 + threadIdx.x;
    if (gid < 3 * 32768) {
        int r = gid >> 15, rem = gid & 32767;
        int j = rem & 7, lane = (rem >> 3) & 63, grp = rem >> 9;
        int kt = grp >> 4, nt = grp & 15;
        int n = (nt & 7) * 16 + (lane & 15);
        int k = kt * 32 + (lane >> 4) * 8 + j;
        int col = ((nt >> 3) << 7) + k;
        Wf[gid] = f2bf(Wm[((size_t)r * 128 + n) * 256 + col]);
    } else if (gid < 3 * 32768 + 256) {
        // Z row N = bf16 -inf: relu(-inf + V) = 0 kills sentinel-pad contributions.
        Z[(size_t)N * 256 + (gid - 3 * 32768)] = 0xFF80;
    }
}

__global__ void convW12_kernel(const float* __restrict__ W1, const float* __restrict__ W2,
                               ushort* __restrict__ Wb12) {
    int gid = blockIdx.x * 256 + threadIdx.x;
    if (gid >= 2 * 16384) return;
    int w = gid >> 14, rem = gid & 16383;
    int n = rem >> 7, k = rem & 127;
    int kt = k >> 5, nt = n >> 4;
    int lane = (n & 15) + (((k >> 3) & 3) << 4);
    int j = k & 7;
    const float* W = w ? W2 : W1;
    Wb12[w * 16384 + ((kt * 8 + nt) * 64 + lane) * 8 + j] = f2bf(W[rem]);
}

// ---- per-round dense GEMM: Z[v][0:128]=A[v]@Wf^T (U), Z[v][128:256]=A[v]@Wt^T+bm (V) ----
__global__ __launch_bounds__(512) void uv_kernel(
    const float* __restrict__ Asrc, ushort* __restrict__ Z,
    const ushort* __restrict__ Wft, const float* __restrict__ bm_r)
{
    __shared__ alignas(16) ushort wlds[32768];   // 64 KB
    const int t = threadIdx.x;

    #pragma unroll
    for (int it = 0; it < 8; ++it) {
        int idx = t + it * 512;
        __builtin_amdgcn_global_load_lds((gbl_void*)(Wft + idx * 8),
                                         (lds_void*)(wlds + idx * 8), 16, 0, 0);
    }

    const int wave = t >> 6, lane = t & 63;
    const int col16 = lane & 15, kq = lane >> 4;
    const int arow = blockIdx.x * 128 + wave * 16 + col16;

    const float4* Ar = reinterpret_cast<const float4*>(Asrc + (size_t)arow * 128);
    float4 areg[8];
    #pragma unroll
    for (int kt = 0; kt < 4; ++kt) {
        areg[2 * kt]     = Ar[kt * 8 + kq * 2];
        areg[2 * kt + 1] = Ar[kt * 8 + kq * 2 + 1];
    }

    f32x4 acc[16];
    #pragma unroll
    for (int nt = 0; nt < 16; ++nt) acc[nt] = (f32x4){0.f, 0.f, 0.f, 0.f};

    __syncthreads();   // wlds ready

    const char* wb = reinterpret_cast<const char*>(wlds);
    #pragma unroll
    for (int kt = 0; kt < 4; ++kt) {
        float4 a0 = areg[2 * kt], a1 = areg[2 * kt + 1];
        union { s16x8 v; ushort u[8]; } pk;
        pk.u[0] = f2bf(a0.x); pk.u[1] = f2bf(a0.y); pk.u[2] = f2bf(a0.z); pk.u[3] = f2bf(a0.w);
        pk.u[4] = f2bf(a1.x); pk.u[5] = f2bf(a1.y); pk.u[6] = f2bf(a1.z); pk.u[7] = f2bf(a1.w);
        #pragma unroll
        for (int nt = 0; nt < 16; ++nt) {
            s16x8 wfr = *reinterpret_cast<const s16x8*>(wb + (((kt * 16 + nt) * 64 + lane) << 4));
            acc[nt] = __builtin_amdgcn_mfma_f32_16x16x32_bf16(wfr, pk.v, acc[nt], 0, 0, 0);
        }
    }

    ushort* zr = Z + (size_t)arow * 256;
    #pragma unroll
    for (int nt = 0; nt < 16; ++nt) {
        float4 bq;
        if (nt >= 8) bq = *reinterpret_cast<const float4*>(bm_r + (nt - 8) * 16 + kq * 4);
        else         bq = (float4){0.f, 0.f, 0.f, 0.f};
        union { uint2 d; ushort u[4]; } pk4;
        pk4.u[0] = f2bf(acc[nt][0] + bq.x);
        pk4.u[1] = f2bf(acc[nt][1] + bq.y);
        pk4.u[2] = f2bf(acc[nt][2] + bq.z);
        pk4.u[3] = f2bf(acc[nt][3] + bq.w);
        int cbase = ((nt >> 3) << 7) + (nt & 7) * 16 + kq * 4;
        *reinterpret_cast<uint2*>(zr + cbase) = pk4.d;
    }
}

// ---- edge pass: 16 nodes/block, 4 nodes/wave; padded sentinel runs + ROLLING idx prefetch ----
// Window [ru4(ends[v-1]), ru4(ends[v])) covers exactly node v's real edges + sentinel pads
// (min-4 padding guarantees no overlap with neighbors' real edges). Inner loop: while
// consuming iter k's 4 U rows, iter k+1's sfrom quad is already in flight -> one memory
// round-trip per 4 edges in steady state.
// L[v] = Lsrc[v] + scale * sum_{e->v} relu(U[from_e] + V[v])
__global__ __launch_bounds__(256) void edge_sum_kernel(
    const ushort* __restrict__ Z, const float* __restrict__ Lsrc, float* __restrict__ Ldst,
    const int* __restrict__ sfrom, const int* __restrict__ ends, const int* __restrict__ ch_ptr)
{
    const int t = threadIdx.x;
    const int wave = t >> 6, lane = t & 63;
    const float scale = 1.0f / (float)(ch_ptr[0] - 1);
    const int v0 = blockIdx.x * 16 + wave * 4;

    int bnd[5];
    bnd[0] = (v0 == 0) ? 0 : ((ends[v0 - 1] + 3) & ~3);
    #pragma unroll
    for (int i = 0; i < 4; ++i) bnd[i + 1] = (ends[v0 + i] + 3) & ~3;

    unsigned vv[4]; float2 lold[4];
    #pragma unroll
    for (int i = 0; i < 4; ++i) {
        vv[i] = *reinterpret_cast<const unsigned*>(Z + (size_t)(v0 + i) * 256 + 128 + lane * 2);
        lold[i] = *reinterpret_cast<const float2*>(Lsrc + (size_t)(v0 + i) * 128 + lane * 2);
    }

    // rolling prefetch seed (bnd[0] is 16B-aligned; sfrom has +64 sentinel tail)
    int4 cur = *reinterpret_cast<const int4*>(sfrom + bnd[0]);

    #pragma unroll
    for (int i = 0; i < 4; ++i) {
        const float vl = bflo(vv[i]), vh = bfhi(vv[i]);
        float a0 = 0.f, a1 = 0.f;
        for (int e = bnd[i]; e < bnd[i + 1]; e += 4) {
            int4 nxt = *reinterpret_cast<const int4*>(sfrom + e + 4);
            unsigned w0 = *reinterpret_cast<const unsigned*>(Z + (size_t)cur.x * 256 + lane * 2);
            unsigned w1 = *reinterpret_cast<const unsigned*>(Z + (size_t)cur.y * 256 + lane * 2);
            unsigned w2 = *reinterpret_cast<const unsigned*>(Z + (size_t)cur.z * 256 + lane * 2);
            unsigned w3 = *reinterpret_cast<const unsigned*>(Z + (size_t)cur.w * 256 + lane * 2);
            a0 += fmaxf(bflo(w0) + vl, 0.f) + fmaxf(bflo(w1) + vl, 0.f)
                + fmaxf(bflo(w2) + vl, 0.f) + fmaxf(bflo(w3) + vl, 0.f);
            a1 += fmaxf(bfhi(w0) + vh, 0.f) + fmaxf(bfhi(w1) + vh, 0.f)
                + fmaxf(bfhi(w2) + vh, 0.f) + fmaxf(bfhi(w3) + vh, 0.f);
            cur = nxt;
        }
        float2 o;
        o.x = lold[i].x + scale * a0;
        o.y = lold[i].y + scale * a1;
        *reinterpret_cast<float2*>(Ldst + (size_t)(v0 + i) * 128 + lane * 2) = o;
    }
}

// ---- segment sum via view-sorted perm: one wave per view, no atomics ----
__global__ __launch_bounds__(256) void segsum_sorted_kernel(
    const float* __restrict__ L, const int* __restrict__ perm,
    const int* __restrict__ vends, float* __restrict__ y)
{
    const int t = threadIdx.x;
    const int wave = t >> 6, lane = t & 63;
    const int v = blockIdx.x * 4 + wave;
    const int lo = (v == 0) ? 0 : vends[v - 1];
    const int hi = vends[v];

    float a0 = 0.f, a1 = 0.f;
    for (int e = lo; e < hi; e += 2) {
        int last = hi - 1;
        int e1 = (e + 1 < hi) ? e + 1 : last;
        float m1 = (e + 1 < hi) ? 1.f : 0.f;
        int n0 = perm[e], n1 = perm[e1];
        float2 x0 = *reinterpret_cast<const float2*>(L + (size_t)n0 * 128 + lane * 2);
        float2 x1 = *reinterpret_cast<const float2*>(L + (size_t)n1 * 128 + lane * 2);
        a0 += x0.x + m1 * x1.x;
        a1 += x0.y + m1 * x1.y;
    }
    float2 o; o.x = a0; o.y = a1;
    *reinterpret_cast<float2*>(y + (size_t)v * 128 + lane * 2) = o;
}

// ---- fused readout: reads y (ws), writes final output to d_out ----
__global__ __launch_bounds__(256) void readout_mfma_kernel(
    const float* __restrict__ y, float* __restrict__ outp,
    const ushort* __restrict__ Wb1, const ushort* __restrict__ Wb2,
    const float* __restrict__ b1, const float* __restrict__ b2)
{
    __shared__ alignas(16) ushort hs[64 * 128];
    const int t = threadIdx.x;
    const int r0 = blockIdx.x * 64;
    char* hbase = reinterpret_cast<char*>(hs);
    const float4* y4 = reinterpret_cast<const float4*>(y);

    #pragma unroll
    for (int it = 0; it < 4; ++it) {
        int c = t + it * 256;
        int e = c >> 4, p = c & 15;
        int g = p ^ (e & 15);
        float4 a = y4[(size_t)(r0 + e) * 32 + g * 2];
        float4 bq = y4[(size_t)(r0 + e) * 32 + g * 2 + 1];
        union { s16x8 v; ushort u[8]; } pk;
        pk.u[0] = f2bf(a.x); pk.u[1] = f2bf(a.y); pk.u[2] = f2bf(a.z); pk.u[3] = f2bf(a.w);
        pk.u[4] = f2bf(bq.x); pk.u[5] = f2bf(bq.y); pk.u[6] = f2bf(bq.z); pk.u[7] = f2bf(bq.w);
        *reinterpret_cast<s16x8*>(hbase + e * 256 + p * 16) = pk.v;
    }
    __syncthreads();

    const int wave = t >> 6, lane = t & 63;
    const int rrow = wave * 16 + (lane & 15);
    const int kq = lane >> 4;
    const int rx = rrow & 15;
    const char* hrow = hbase + rrow * 256;
    const int col16 = lane & 15;

    f32x4 acc[8];
    #pragma unroll
    for (int nt = 0; nt < 8; ++nt) acc[nt] = (f32x4){0.f, 0.f, 0.f, 0.f};
    const s16x8* wf1 = reinterpret_cast<const s16x8*>(Wb1);
    #pragma unroll
    for (int kt = 0; kt < 4; ++kt) {
        int C = kt * 4 + kq;
        s16x8 a = *reinterpret_cast<const s16x8*>(hrow + ((C ^ rx) & 15) * 16);
        #pragma unroll
        for (int nt = 0; nt < 8; ++nt)
            acc[nt] = __builtin_amdgcn_mfma_f32_16x16x32_bf16(a, wf1[(kt * 8 + nt) * 64 + lane], acc[nt], 0, 0, 0);
    }
    __syncthreads();

    #pragma unroll
    for (int nt = 0; nt < 8; ++nt) {
        float bias = b1[nt * 16 + col16];
        #pragma unroll
        for (int j = 0; j < 4; ++j) {
            int r = wave * 16 + (lane >> 4) * 4 + j;
            float h = fmaxf(acc[nt][j] + bias, 0.f);
            int colfull = nt * 16 + col16;
            int chunk = colfull >> 3;
            int bo = ((chunk ^ (r & 15)) * 16) + (colfull & 7) * 2;
            *reinterpret_cast<ushort*>(hbase + r * 256 + bo) = f2bf(h);
        }
    }
    __syncthreads();

    f32x4 acc2[8];
    #pragma unroll
    for (int nt = 0; nt < 8; ++nt) acc2[nt] = (f32x4){0.f, 0.f, 0.f, 0.f};
    const s16x8* wf2 = reinterpret_cast<const s16x8*>(Wb2);
    #pragma unroll
    for (int kt = 0; kt < 4; ++kt) {
        int C = kt * 4 + kq;
        s16x8 a = *reinterpret_cast<const s16x8*>(hrow + ((C ^ rx) & 15) * 16);
        #pragma unroll
        for (int nt = 0; nt < 8; ++nt)
            acc2[nt] = __builtin_amdgcn_mfma_f32_16x16x32_bf16(a, wf2[(kt * 8 + nt) * 64 + lane], acc2[nt], 0, 0, 0);
    }

    #pragma unroll
    for (int nt = 0; nt < 8; ++nt) {
        float bias = b2[nt * 16 + col16];
        #pragma unroll
        for (int j = 0; j < 4; ++j) {
            int r = r0 + wave * 16 + (lane >> 4) * 4 + j;
            outp[(size_t)r * 128 + nt * 16 + col16] = acc2[nt][j] + bias;
        }
    }
}

extern "C" void kernel_launch(void* const* d_in, const int* in_sizes, int n_in,
                              void* d_out, int out_size, void* d_ws, size_t ws_size,
                              hipStream_t stream) {
    const float* latents = (const float*)d_in[0];
    const float* Wm      = (const float*)d_in[1];
    const float* bm      = (const float*)d_in[2];
    const float* W1      = (const float*)d_in[3];
    const float* b1      = (const float*)d_in[4];
    const float* W2      = (const float*)d_in[5];
    const float* b2      = (const float*)d_in[6];
    const int*   efrom   = (const int*)d_in[7];
    const int*   eto     = (const int*)d_in[8];
    const int*   view    = (const int*)d_in[9];
    const int*   ch      = (const int*)d_in[10];

    // ws (100.66 MB, proven): L f32[N*128] | Z bf16[(N+1)*256] (row N = -inf sentinel).
    // After final edge_sum Z rows [0,N) are dead: y f32[B*128] and Wb12 reuse them.
    float*  L  = (float*)d_ws;
    ushort* Z  = (ushort*)(L + (size_t)N * D);
    float*  yb = (float*)Z;                              // B*128 f32 = 8.39 MB
    ushort* Wb12 = (ushort*)((char*)Z + 8388608);        // 64 KB

    // d_out scratch (readout is d_out's only writer, covers all of it):
    char* ob = (char*)d_out;
    ushort* WUVf = (ushort*)ob;                          // 196,608 B
    int* cnt   = (int*)(ob + 196608);                    // N
    int* vcnt  = cnt + N;                                // B
    int* excl  = vcnt + B;                               // N
    int* vexcl = excl + N;                               // B
    int* bsum  = vexcl + B;                              // 112 (+pad to 128)
    int* sfrom = bsum + 128;                             // SFN (padded, 16B-aligned)
    int* perm  = sfrom + SFN;                            // N    (total ~5.0 MB < 8.39 MB)
    float* outp = (float*)d_out;

    // Setup: weight frags (+Z sentinel row) + sentinel-prefilled dual counting sort.
    convUV_kernel<<<385, 256, 0, stream>>>(Wm, WUVf, Z);
    setup_fill_kernel<<<2048, 256, 0, stream>>>(cnt, sfrom);
    hist2_kernel<<<(E + N) / 256, 256, 0, stream>>>(eto, view, cnt, vcnt);
    scan1_kernel<<<112, 256, 0, stream>>>(cnt, excl, vcnt, vexcl, bsum);
    scan2_kernel<<<1, 128, 0, stream>>>(bsum);
    scan3_kernel<<<448, 256, 0, stream>>>(excl, vexcl, bsum);
    scatter2_kernel<<<(E + N) / 256, 256, 0, stream>>>(efrom, eto, view, excl, vexcl, sfrom, perm);
    // post-scatter: excl[v] = pstart[v]+deg[v]; pads remain sentinel N

    // Three message-passing rounds.
    uv_kernel<<<N / 128, 512, 0, stream>>>(latents, Z, WUVf, bm);
    edge_sum_kernel<<<N / 16, 256, 0, stream>>>(Z, latents, L, sfrom, excl, ch);
    uv_kernel<<<N / 128, 512, 0, stream>>>(L, Z, WUVf + 32768, bm + D);
    edge_sum_kernel<<<N / 16, 256, 0, stream>>>(Z, L, L, sfrom, excl, ch);
    uv_kernel<<<N / 128, 512, 0, stream>>>(L, Z, WUVf + 65536, bm + 2 * D);
    edge_sum_kernel<<<N / 16, 256, 0, stream>>>(Z, L, L, sfrom, excl, ch);

    // Readout: Z dead -> yb/Wb12 live there.
    convW12_kernel<<<128, 256, 0, stream>>>(W1, W2, Wb12);
    segsum_sorted_kernel<<<B / 4, 256, 0, stream>>>(L, perm, vexcl, yb);
    readout_mfma_kernel<<<B / 64, 256, 0, stream>>>(yb, outp, Wb12, Wb12 + 16384, b1, b2);
}

// Round 12
// 285.530 us; speedup vs baseline: 1.0828x; 1.0044x over previous
//
#include <hip/hip_runtime.h>

static constexpr int N  = 98304;
static constexpr int D  = 128;
static constexpr int E  = 491520;
static constexpr int B  = 16384;
static constexpr int SFN = E + 7 * N + 64;   // pad-to-8 sfrom capacity

using f32x4 = __attribute__((ext_vector_type(4))) float;
using s16x8 = __attribute__((ext_vector_type(8))) short;

typedef __attribute__((address_space(3))) void lds_void;
typedef const __attribute__((address_space(1))) void gbl_void;

__device__ __forceinline__ ushort f2bf(float x) {
    unsigned u = __float_as_uint(x);
    return (ushort)((u + 0x7fffu + ((u >> 16) & 1u)) >> 16);
}
__device__ __forceinline__ float bflo(unsigned u) { return __uint_as_float(u << 16); }
__device__ __forceinline__ float bfhi(unsigned u) { return __uint_as_float(u & 0xffff0000u); }

// ---- setup: zero histograms AND pre-fill sfrom with sentinel N ----
__global__ void setup_fill_kernel(int* __restrict__ cnt, int* __restrict__ sfrom) {
    int i = blockIdx.x * blockDim.x + threadIdx.x;
    int stride = gridDim.x * blockDim.x;
    for (int j = i; j < N + B; j += stride) cnt[j] = 0;
    for (int j = i; j < SFN; j += stride) sfrom[j] = N;
}

// ---- dual histogram: edges by dest, nodes by view ----
__global__ void hist2_kernel(const int* __restrict__ eto, const int* __restrict__ view,
                             int* __restrict__ cnt, int* __restrict__ vcnt) {
    int gid = blockIdx.x * 256 + threadIdx.x;
    if (gid < E) atomicAdd(&cnt[eto[gid]], 1);
    else if (gid < E + N) atomicAdd(&vcnt[view[gid - E]], 1);
}

// ---- dual scan, stage 1: blocks 0..95 nodes (pad to roundup8), 96..111 views ----
__global__ __launch_bounds__(256) void scan1_kernel(const int* __restrict__ cnt, int* __restrict__ excl,
                                                    const int* __restrict__ vcnt, int* __restrict__ vexcl,
                                                    int* __restrict__ bsum) {
    __shared__ int s[256];
    const int b = blockIdx.x, t = threadIdx.x;
    const int* src; int* dst; int base;
    bool pad = (b < 96);
    if (pad) { src = cnt;  dst = excl;  base = b * 1024 + t * 4; }
    else     { src = vcnt; dst = vexcl; base = (b - 96) * 1024 + t * 4; }
    int4 v = *reinterpret_cast<const int4*>(src + base);
    if (pad) {
        v.x = (v.x + 7) & ~7; v.y = (v.y + 7) & ~7;
        v.z = (v.z + 7) & ~7; v.w = (v.w + 7) & ~7;
    }
    int local = v.x + v.y + v.z + v.w;
    s[t] = local; __syncthreads();
    for (int off = 1; off < 256; off <<= 1) {
        int x = (t >= off) ? s[t - off] : 0;
        __syncthreads();
        s[t] += x;
        __syncthreads();
    }
    int excl_t = s[t] - local;
    if (t == 255) bsum[b] = s[t];
    int4 o;
    o.x = excl_t; o.y = o.x + v.x; o.z = o.y + v.y; o.w = o.z + v.z;
    *reinterpret_cast<int4*>(dst + base) = o;
}

// Parallel dual-segment scan of bsum[0..95] and bsum[96..111].
__global__ __launch_bounds__(128) void scan2_kernel(int* __restrict__ bsum) {
    __shared__ int s[128];
    const int t = threadIdx.x;
    int val = (t < 112) ? bsum[t] : 0;
    s[t] = val;
    __syncthreads();
    #pragma unroll
    for (int off = 1; off < 128; off <<= 1) {
        int x = (t >= off) ? s[t - off] : 0;
        __syncthreads();
        s[t] += x;
        __syncthreads();
    }
    int incl = s[t];
    int seg0_total = s[95];
    int excl = incl - val;
    if (t < 96) bsum[t] = excl;
    else if (t < 112) bsum[t] = excl - seg0_total;
}

__global__ void scan3_kernel(int* __restrict__ excl, int* __restrict__ vexcl,
                             const int* __restrict__ bsum) {
    int b = blockIdx.x, t = threadIdx.x;
    if (b < 384) { int i = b * 256 + t; excl[i] += bsum[i >> 10]; }
    else         { int i = (b - 384) * 256 + t; vexcl[i] += bsum[96 + (i >> 10)]; }
}

__global__ void scatter2_kernel(const int* __restrict__ efrom, const int* __restrict__ eto,
                                const int* __restrict__ view,
                                int* __restrict__ ecur, int* __restrict__ vcur,
                                int* __restrict__ sfrom, int* __restrict__ perm) {
    int gid = blockIdx.x * 256 + threadIdx.x;
    if (gid < E) {
        int p = atomicAdd(&ecur[eto[gid]], 1);
        sfrom[p] = efrom[gid];
    } else if (gid < E + N) {
        int n = gid - E;
        int p = atomicAdd(&vcur[view[n]], 1);
        perm[p] = n;
    }
}

// ---- weight conversion (+ Z sentinel row write, folded in) ----
__global__ void convUV_kernel(const float* __restrict__ Wm, ushort* __restrict__ Wf,
                              ushort* __restrict__ Z) {
    int gid = blockIdx.x * 256 + threadIdx.x;
    if (gid < 3 * 32768) {
        int r = gid >> 15, rem = gid & 32767;
        int j = rem & 7, lane = (rem >> 3) & 63, grp = rem >> 9;
        int kt = grp >> 4, nt = grp & 15;
        int n = (nt & 7) * 16 + (lane & 15);
        int k = kt * 32 + (lane >> 4) * 8 + j;
        int col = ((nt >> 3) << 7) + k;
        Wf[gid] = f2bf(Wm[((size_t)r * 128 + n) * 256 + col]);
    } else if (gid < 3 * 32768 + 256) {
        // Z row N = bf16 -inf: relu(-inf + V) = 0 kills sentinel-pad contributions.
        Z[(size_t)N * 256 + (gid - 3 * 32768)] = 0xFF80;
    }
}

__global__ void convW12_kernel(const float* __restrict__ W1, const float* __restrict__ W2,
                               ushort* __restrict__ Wb12) {
    int gid = blockIdx.x * 256 + threadIdx.x;
    if (gid >= 2 * 16384) return;
    int w = gid >> 14, rem = gid & 16383;
    int n = rem >> 7, k = rem & 127;
    int kt = k >> 5, nt = n >> 4;
    int lane = (n & 15) + (((k >> 3) & 3) << 4);
    int j = k & 7;
    const float* W = w ? W2 : W1;
    Wb12[w * 16384 + ((kt * 8 + nt) * 64 + lane) * 8 + j] = f2bf(W[rem]);
}

// ---- per-round dense GEMM: Z[v][0:128]=A[v]@Wf^T (U), Z[v][128:256]=A[v]@Wt^T+bm (V) ----
__global__ __launch_bounds__(512) void uv_kernel(
    const float* __restrict__ Asrc, ushort* __restrict__ Z,
    const ushort* __restrict__ Wft, const float* __restrict__ bm_r)
{
    __shared__ alignas(16) ushort wlds[32768];   // 64 KB
    const int t = threadIdx.x;

    #pragma unroll
    for (int it = 0; it < 8; ++it) {
        int idx = t + it * 512;
        __builtin_amdgcn_global_load_lds((gbl_void*)(Wft + idx * 8),
                                         (lds_void*)(wlds + idx * 8), 16, 0, 0);
    }

    const int wave = t >> 6, lane = t & 63;
    const int col16 = lane & 15, kq = lane >> 4;
    const int arow = blockIdx.x * 128 + wave * 16 + col16;

    const float4* Ar = reinterpret_cast<const float4*>(Asrc + (size_t)arow * 128);
    float4 areg[8];
    #pragma unroll
    for (int kt = 0; kt < 4; ++kt) {
        areg[2 * kt]     = Ar[kt * 8 + kq * 2];
        areg[2 * kt + 1] = Ar[kt * 8 + kq * 2 + 1];
    }

    f32x4 acc[16];
    #pragma unroll
    for (int nt = 0; nt < 16; ++nt) acc[nt] = (f32x4){0.f, 0.f, 0.f, 0.f};

    __syncthreads();   // wlds ready

    const char* wb = reinterpret_cast<const char*>(wlds);
    #pragma unroll
    for (int kt = 0; kt < 4; ++kt) {
        float4 a0 = areg[2 * kt], a1 = areg[2 * kt + 1];
        union { s16x8 v; ushort u[8]; } pk;
        pk.u[0] = f2bf(a0.x); pk.u[1] = f2bf(a0.y); pk.u[2] = f2bf(a0.z); pk.u[3] = f2bf(a0.w);
        pk.u[4] = f2bf(a1.x); pk.u[5] = f2bf(a1.y); pk.u[6] = f2bf(a1.z); pk.u[7] = f2bf(a1.w);
        #pragma unroll
        for (int nt = 0; nt < 16; ++nt) {
            s16x8 wfr = *reinterpret_cast<const s16x8*>(wb + (((kt * 16 + nt) * 64 + lane) << 4));
            acc[nt] = __builtin_amdgcn_mfma_f32_16x16x32_bf16(wfr, pk.v, acc[nt], 0, 0, 0);
        }
    }

    ushort* zr = Z + (size_t)arow * 256;
    #pragma unroll
    for (int nt = 0; nt < 16; ++nt) {
        float4 bq;
        if (nt >= 8) bq = *reinterpret_cast<const float4*>(bm_r + (nt - 8) * 16 + kq * 4);
        else         bq = (float4){0.f, 0.f, 0.f, 0.f};
        union { uint2 d; ushort u[4]; } pk4;
        pk4.u[0] = f2bf(acc[nt][0] + bq.x);
        pk4.u[1] = f2bf(acc[nt][1] + bq.y);
        pk4.u[2] = f2bf(acc[nt][2] + bq.z);
        pk4.u[3] = f2bf(acc[nt][3] + bq.w);
        int cbase = ((nt >> 3) << 7) + (nt & 7) * 16 + kq * 4;
        *reinterpret_cast<uint2*>(zr + cbase) = pk4.d;
    }
}

// ---- edge pass: 16 nodes/block, 4 nodes/wave; pad-to-8 sentinel runs, 8-wide ----
// Windows [ru8(ends[v-1]), ru8(ends[v])) tile exactly (pad = roundup8(deg), deg0 -> 0
// slots), so the rolling carry c0/c1 stays valid across node boundaries. Steady state:
// one memory round-trip per 8 edges; 8 U loads + 2 idx loads in flight.
// L[v] = Lsrc[v] + scale * sum_{e->v} relu(U[from_e] + V[v])
__global__ __launch_bounds__(256) void edge_sum_kernel(
    const ushort* __restrict__ Z, const float* __restrict__ Lsrc, float* __restrict__ Ldst,
    const int* __restrict__ sfrom, const int* __restrict__ ends, const int* __restrict__ ch_ptr)
{
    const int t = threadIdx.x;
    const int wave = t >> 6, lane = t & 63;
    const float scale = 1.0f / (float)(ch_ptr[0] - 1);
    const int v0 = blockIdx.x * 16 + wave * 4;

    int bnd[5];
    bnd[0] = (v0 == 0) ? 0 : ((ends[v0 - 1] + 7) & ~7);
    #pragma unroll
    for (int i = 0; i < 4; ++i) bnd[i + 1] = (ends[v0 + i] + 7) & ~7;

    unsigned vv[4]; float2 lold[4];
    #pragma unroll
    for (int i = 0; i < 4; ++i) {
        vv[i] = *reinterpret_cast<const unsigned*>(Z + (size_t)(v0 + i) * 256 + 128 + lane * 2);
        lold[i] = *reinterpret_cast<const float2*>(Lsrc + (size_t)(v0 + i) * 128 + lane * 2);
    }

    // rolling prefetch seed (bnd[0] is 32B-aligned; sfrom has +64 sentinel tail)
    int4 c0 = *reinterpret_cast<const int4*>(sfrom + bnd[0]);
    int4 c1 = *reinterpret_cast<const int4*>(sfrom + bnd[0] + 4);

    #pragma unroll
    for (int i = 0; i < 4; ++i) {
        const float vl = bflo(vv[i]), vh = bfhi(vv[i]);
        float a0 = 0.f, a1 = 0.f;
        for (int e = bnd[i]; e < bnd[i + 1]; e += 8) {
            int4 n0 = *reinterpret_cast<const int4*>(sfrom + e + 8);
            int4 n1 = *reinterpret_cast<const int4*>(sfrom + e + 12);
            unsigned w0 = *reinterpret_cast<const unsigned*>(Z + (size_t)c0.x * 256 + lane * 2);
            unsigned w1 = *reinterpret_cast<const unsigned*>(Z + (size_t)c0.y * 256 + lane * 2);
            unsigned w2 = *reinterpret_cast<const unsigned*>(Z + (size_t)c0.z * 256 + lane * 2);
            unsigned w3 = *reinterpret_cast<const unsigned*>(Z + (size_t)c0.w * 256 + lane * 2);
            unsigned w4 = *reinterpret_cast<const unsigned*>(Z + (size_t)c1.x * 256 + lane * 2);
            unsigned w5 = *reinterpret_cast<const unsigned*>(Z + (size_t)c1.y * 256 + lane * 2);
            unsigned w6 = *reinterpret_cast<const unsigned*>(Z + (size_t)c1.z * 256 + lane * 2);
            unsigned w7 = *reinterpret_cast<const unsigned*>(Z + (size_t)c1.w * 256 + lane * 2);
            a0 += fmaxf(bflo(w0) + vl, 0.f) + fmaxf(bflo(w1) + vl, 0.f)
                + fmaxf(bflo(w2) + vl, 0.f) + fmaxf(bflo(w3) + vl, 0.f)
                + fmaxf(bflo(w4) + vl, 0.f) + fmaxf(bflo(w5) + vl, 0.f)
                + fmaxf(bflo(w6) + vl, 0.f) + fmaxf(bflo(w7) + vl, 0.f);
            a1 += fmaxf(bfhi(w0) + vh, 0.f) + fmaxf(bfhi(w1) + vh, 0.f)
                + fmaxf(bfhi(w2) + vh, 0.f) + fmaxf(bfhi(w3) + vh, 0.f)
                + fmaxf(bfhi(w4) + vh, 0.f) + fmaxf(bfhi(w5) + vh, 0.f)
                + fmaxf(bfhi(w6) + vh, 0.f) + fmaxf(bfhi(w7) + vh, 0.f);
            c0 = n0; c1 = n1;
        }
        float2 o;
        o.x = lold[i].x + scale * a0;
        o.y = lold[i].y + scale * a1;
        *reinterpret_cast<float2*>(Ldst + (size_t)(v0 + i) * 128 + lane * 2) = o;
    }
}

// ---- segment sum via view-sorted perm: one wave per view, no atomics ----
__global__ __launch_bounds__(256) void segsum_sorted_kernel(
    const float* __restrict__ L, const int* __restrict__ perm,
    const int* __restrict__ vends, float* __restrict__ y)
{
    const int t = threadIdx.x;
    const int wave = t >> 6, lane = t & 63;
    const int v = blockIdx.x * 4 + wave;
    const int lo = (v == 0) ? 0 : vends[v - 1];
    const int hi = vends[v];

    float a0 = 0.f, a1 = 0.f;
    for (int e = lo; e < hi; e += 2) {
        int last = hi - 1;
        int e1 = (e + 1 < hi) ? e + 1 : last;
        float m1 = (e + 1 < hi) ? 1.f : 0.f;
        int n0 = perm[e], n1 = perm[e1];
        float2 x0 = *reinterpret_cast<const float2*>(L + (size_t)n0 * 128 + lane * 2);
        float2 x1 = *reinterpret_cast<const float2*>(L + (size_t)n1 * 128 + lane * 2);
        a0 += x0.x + m1 * x1.x;
        a1 += x0.y + m1 * x1.y;
    }
    float2 o; o.x = a0; o.y = a1;
    *reinterpret_cast<float2*>(y + (size_t)v * 128 + lane * 2) = o;
}

// ---- fused readout: reads y (ws), writes final output to d_out ----
__global__ __launch_bounds__(256) void readout_mfma_kernel(
    const float* __restrict__ y, float* __restrict__ outp,
    const ushort* __restrict__ Wb1, const ushort* __restrict__ Wb2,
    const float* __restrict__ b1, const float* __restrict__ b2)
{
    __shared__ alignas(16) ushort hs[64 * 128];
    const int t = threadIdx.x;
    const int r0 = blockIdx.x * 64;
    char* hbase = reinterpret_cast<char*>(hs);
    const float4* y4 = reinterpret_cast<const float4*>(y);

    #pragma unroll
    for (int it = 0; it < 4; ++it) {
        int c = t + it * 256;
        int e = c >> 4, p = c & 15;
        int g = p ^ (e & 15);
        float4 a = y4[(size_t)(r0 + e) * 32 + g * 2];
        float4 bq = y4[(size_t)(r0 + e) * 32 + g * 2 + 1];
        union { s16x8 v; ushort u[8]; } pk;
        pk.u[0] = f2bf(a.x); pk.u[1] = f2bf(a.y); pk.u[2] = f2bf(a.z); pk.u[3] = f2bf(a.w);
        pk.u[4] = f2bf(bq.x); pk.u[5] = f2bf(bq.y); pk.u[6] = f2bf(bq.z); pk.u[7] = f2bf(bq.w);
        *reinterpret_cast<s16x8*>(hbase + e * 256 + p * 16) = pk.v;
    }
    __syncthreads();

    const int wave = t >> 6, lane = t & 63;
    const int rrow = wave * 16 + (lane & 15);
    const int kq = lane >> 4;
    const int rx = rrow & 15;
    const char* hrow = hbase + rrow * 256;
    const int col16 = lane & 15;

    f32x4 acc[8];
    #pragma unroll
    for (int nt = 0; nt < 8; ++nt) acc[nt] = (f32x4){0.f, 0.f, 0.f, 0.f};
    const s16x8* wf1 = reinterpret_cast<const s16x8*>(Wb1);
    #pragma unroll
    for (int kt = 0; kt < 4; ++kt) {
        int C = kt * 4 + kq;
        s16x8 a = *reinterpret_cast<const s16x8*>(hrow + ((C ^ rx) & 15) * 16);
        #pragma unroll
        for (int nt = 0; nt < 8; ++nt)
            acc[nt] = __builtin_amdgcn_mfma_f32_16x16x32_bf16(a, wf1[(kt * 8 + nt) * 64 + lane], acc[nt], 0, 0, 0);
    }
    __syncthreads();

    #pragma unroll
    for (int nt = 0; nt < 8; ++nt) {
        float bias = b1[nt * 16 + col16];
        #pragma unroll
        for (int j = 0; j < 4; ++j) {
            int r = wave * 16 + (lane >> 4) * 4 + j;
            float h = fmaxf(acc[nt][j] + bias, 0.f);
            int colfull = nt * 16 + col16;
            int chunk = colfull >> 3;
            int bo = ((chunk ^ (r & 15)) * 16) + (colfull & 7) * 2;
            *reinterpret_cast<ushort*>(hbase + r * 256 + bo) = f2bf(h);
        }
    }
    __syncthreads();

    f32x4 acc2[8];
    #pragma unroll
    for (int nt = 0; nt < 8; ++nt) acc2[nt] = (f32x4){0.f, 0.f, 0.f, 0.f};
    const s16x8* wf2 = reinterpret_cast<const s16x8*>(Wb2);
    #pragma unroll
    for (int kt = 0; kt < 4; ++kt) {
        int C = kt * 4 + kq;
        s16x8 a = *reinterpret_cast<const s16x8*>(hrow + ((C ^ rx) & 15) * 16);
        #pragma unroll
        for (int nt = 0; nt < 8; ++nt)
            acc2[nt] = __builtin_amdgcn_mfma_f32_16x16x32_bf16(a, wf2[(kt * 8 + nt) * 64 + lane], acc2[nt], 0, 0, 0);
    }

    #pragma unroll
    for (int nt = 0; nt < 8; ++nt) {
        float bias = b2[nt * 16 + col16];
        #pragma unroll
        for (int j = 0; j < 4; ++j) {
            int r = r0 + wave * 16 + (lane >> 4) * 4 + j;
            outp[(size_t)r * 128 + nt * 16 + col16] = acc2[nt][j] + bias;
        }
    }
}

extern "C" void kernel_launch(void* const* d_in, const int* in_sizes, int n_in,
                              void* d_out, int out_size, void* d_ws, size_t ws_size,
                              hipStream_t stream) {
    const float* latents = (const float*)d_in[0];
    const float* Wm      = (const float*)d_in[1];
    const float* bm      = (const float*)d_in[2];
    const float* W1      = (const float*)d_in[3];
    const float* b1      = (const float*)d_in[4];
    const float* W2      = (const float*)d_in[5];
    const float* b2      = (const float*)d_in[6];
    const int*   efrom   = (const int*)d_in[7];
    const int*   eto     = (const int*)d_in[8];
    const int*   view    = (const int*)d_in[9];
    const int*   ch      = (const int*)d_in[10];

    // ws (100.66 MB, proven): L f32[N*128] | Z bf16[(N+1)*256] (row N = -inf sentinel).
    // After final edge_sum Z rows [0,N) are dead: y f32[B*128] and Wb12 reuse them.
    float*  L  = (float*)d_ws;
    ushort* Z  = (ushort*)(L + (size_t)N * D);
    float*  yb = (float*)Z;                              // B*128 f32 = 8.39 MB
    ushort* Wb12 = (ushort*)((char*)Z + 8388608);        // 64 KB

    // d_out scratch (readout is d_out's only writer, covers all of it):
    char* ob = (char*)d_out;
    ushort* WUVf = (ushort*)ob;                          // 196,608 B
    int* cnt   = (int*)(ob + 196608);                    // N
    int* vcnt  = cnt + N;                                // B
    int* excl  = vcnt + B;                               // N
    int* vexcl = excl + N;                               // B
    int* bsum  = vexcl + B;                              // 112 (+pad to 128)
    int* sfrom = bsum + 128;                             // SFN (pad-to-8, 32B-aligned)
    int* perm  = sfrom + SFN;                            // N    (total ~6.3 MB < 8.39 MB)
    float* outp = (float*)d_out;

    // Setup: weight frags (+Z sentinel row) + sentinel-prefilled dual counting sort.
    convUV_kernel<<<385, 256, 0, stream>>>(Wm, WUVf, Z);
    setup_fill_kernel<<<2048, 256, 0, stream>>>(cnt, sfrom);
    hist2_kernel<<<(E + N) / 256, 256, 0, stream>>>(eto, view, cnt, vcnt);
    scan1_kernel<<<112, 256, 0, stream>>>(cnt, excl, vcnt, vexcl, bsum);
    scan2_kernel<<<1, 128, 0, stream>>>(bsum);
    scan3_kernel<<<448, 256, 0, stream>>>(excl, vexcl, bsum);
    scatter2_kernel<<<(E + N) / 256, 256, 0, stream>>>(efrom, eto, view, excl, vexcl, sfrom, perm);
    // post-scatter: excl[v] = pstart[v]+deg[v]; pads remain sentinel N

    // Three message-passing rounds.
    uv_kernel<<<N / 128, 512, 0, stream>>>(latents, Z, WUVf, bm);
    edge_sum_kernel<<<N / 16, 256, 0, stream>>>(Z, latents, L, sfrom, excl, ch);
    uv_kernel<<<N / 128, 512, 0, stream>>>(L, Z, WUVf + 32768, bm + D);
    edge_sum_kernel<<<N / 16, 256, 0, stream>>>(Z, L, L, sfrom, excl, ch);
    uv_kernel<<<N / 128, 512, 0, stream>>>(L, Z, WUVf + 65536, bm + 2 * D);
    edge_sum_kernel<<<N / 16, 256, 0, stream>>>(Z, L, L, sfrom, excl, ch);

    // Readout: Z dead -> yb/Wb12 live there.
    convW12_kernel<<<128, 256, 0, stream>>>(W1, W2, Wb12);
    segsum_sorted_kernel<<<B / 4, 256, 0, stream>>>(L, perm, vexcl, yb);
    readout_mfma_kernel<<<B / 64, 256, 0, stream>>>(yb, outp, Wb12, Wb12 + 16384, b1, b2);
}